// Round 1
// baseline (194.713 us; speedup 1.0000x reference)
//
#include <hip/hip_runtime.h>
#include <math.h>

// Problem constants (EnhancedLDEPooling): x (B,T,D) fp32, centers (K,D), scale (K), temperature ()
#define BB 16
#define TT 2048
#define DD 256
#define KK 8
static constexpr float LN_EPS = 1e-5f;

// ---------------------------------------------------------------------------
// Kernel 1: per-(b, T-chunk) block accumulates s_w (K), s_wx (K,D), s_wx2 (K,D)
// Block = 512 threads = 8 waves. Each wave processes whole tokens:
// lane l owns d = 4l..4l+3 (one float4 per token, coalesced 1KB/wave load).
// Per-wave register accumulators -> LDS combine -> per-block partial to ws.
// ---------------------------------------------------------------------------
__global__ __launch_bounds__(512) void lde_accum(
    const float* __restrict__ x,
    const float* __restrict__ centers,
    const float* __restrict__ scale,
    const float* __restrict__ temperature,
    float* __restrict__ ws_wx,   // [B*C][K][512]  (0..255 = wx, 256..511 = wx2)
    float* __restrict__ ws_w,    // [B*C][K]
    int C)
{
    const int c    = blockIdx.x;
    const int b    = blockIdx.y;
    const int tid  = threadIdx.x;
    const int wave = tid >> 6;
    const int lane = tid & 63;

    const int TC  = TT / C;          // tokens per block
    const int TPW = TC >> 3;         // tokens per wave (8 waves)
    const int t0  = c * TC + wave * TPW;

    // LDS combine buffer: [K][512] (wx | wx2) + [K] w
    __shared__ float lds_acc[KK * 512];
    __shared__ float lds_w[KK];
    for (int i = tid; i < KK * 512; i += 512) lds_acc[i] = 0.0f;
    if (tid < KK) lds_w[tid] = 0.0f;

    // Center fragments in registers: c4[k] = centers[k][4*lane .. 4*lane+3]
    const float4* cvec = reinterpret_cast<const float4*>(centers);
    float4 c4[KK];
    float  c2[KK];
    #pragma unroll
    for (int k = 0; k < KK; ++k) {
        c4[k] = cvec[k * 64 + lane];
        float p = c4[k].x * c4[k].x + c4[k].y * c4[k].y
                + c4[k].z * c4[k].z + c4[k].w * c4[k].w;
        #pragma unroll
        for (int off = 32; off >= 1; off >>= 1) p += __shfl_xor(p, off, 64);
        c2[k] = p;
    }
    const float temp = temperature[0];
    float ts[KK];
    #pragma unroll
    for (int k = 0; k < KK; ++k) ts[k] = temp * scale[k];

    float accw[KK]      = {};
    float accwx[KK][4]  = {};
    float accwx2[KK][4] = {};

    const float4* xrow = reinterpret_cast<const float4*>(x + (size_t)b * TT * DD);

    // Software-pipelined token loop (prefetch next token's float4)
    float4 xv = xrow[t0 * 64 + lane];
    for (int i = 0; i < TPW; ++i) {
        float4 cur = xv;
        if (i + 1 < TPW) xv = xrow[(t0 + i + 1) * 64 + lane];

        // per-lane partials: dots vs 8 centers + ||x||^2
        float r[KK + 1];
        r[KK] = cur.x * cur.x + cur.y * cur.y + cur.z * cur.z + cur.w * cur.w;
        #pragma unroll
        for (int k = 0; k < KK; ++k) {
            r[k] = cur.x * c4[k].x + cur.y * c4[k].y
                 + cur.z * c4[k].z + cur.w * c4[k].w;
        }
        // 9-value wave butterfly -> every lane has full sums
        #pragma unroll
        for (int off = 32; off >= 1; off >>= 1) {
            #pragma unroll
            for (int v = 0; v <= KK; ++v) r[v] += __shfl_xor(r[v], off, 64);
        }
        const float x2 = r[KK];

        // softmax over K (computed redundantly in every lane)
        float logit[KK];
        float m = -3.4e38f;
        #pragma unroll
        for (int k = 0; k < KK; ++k) {
            float dist = x2 - 2.0f * r[k] + c2[k];
            logit[k] = -ts[k] * dist;
            m = fmaxf(m, logit[k]);
        }
        float s = 0.0f;
        float p[KK];
        #pragma unroll
        for (int k = 0; k < KK; ++k) { p[k] = __expf(logit[k] - m); s += p[k]; }
        const float inv = 1.0f / s;

        float xx[4] = {cur.x * cur.x, cur.y * cur.y, cur.z * cur.z, cur.w * cur.w};
        #pragma unroll
        for (int k = 0; k < KK; ++k) {
            const float w = p[k] * inv;
            accw[k] += w;
            accwx[k][0]  += w * cur.x;  accwx[k][1]  += w * cur.y;
            accwx[k][2]  += w * cur.z;  accwx[k][3]  += w * cur.w;
            accwx2[k][0] += w * xx[0];  accwx2[k][1] += w * xx[1];
            accwx2[k][2] += w * xx[2];  accwx2[k][3] += w * xx[3];
        }
    }

    __syncthreads();  // zeroing + all waves done accumulating

    // LDS combine; stagger k by wave to cut 8-way same-address contention
    #pragma unroll
    for (int kk = 0; kk < KK; ++kk) {
        const int k = (kk + wave) & (KK - 1);
        float* wxp  = &lds_acc[k * 512 + 4 * lane];
        float* wx2p = &lds_acc[k * 512 + 256 + 4 * lane];
        atomicAdd(&wxp[0],  accwx[k][0]);  atomicAdd(&wxp[1],  accwx[k][1]);
        atomicAdd(&wxp[2],  accwx[k][2]);  atomicAdd(&wxp[3],  accwx[k][3]);
        atomicAdd(&wx2p[0], accwx2[k][0]); atomicAdd(&wx2p[1], accwx2[k][1]);
        atomicAdd(&wx2p[2], accwx2[k][2]); atomicAdd(&wx2p[3], accwx2[k][3]);
        if (lane == 0) atomicAdd(&lds_w[k], accw[k]);
    }
    __syncthreads();

    // write per-block partial (coalesced)
    float* dst = ws_wx + ((size_t)(b * C + c) * KK) * 512;
    for (int i = tid; i < KK * 512; i += 512) dst[i] = lds_acc[i];
    if (tid < KK) ws_w[(size_t)(b * C + c) * KK + tid] = lds_w[tid];
}

// ---------------------------------------------------------------------------
// Kernel 2: one block per (b,k). Sum partials over C, form mean/var with the
// reference's exact decomposition, layer-norm over the 512-vector, write out.
// ---------------------------------------------------------------------------
__global__ __launch_bounds__(256) void lde_final(
    const float* __restrict__ ws_wx,
    const float* __restrict__ ws_w,
    const float* __restrict__ centers,
    float* __restrict__ out,
    int C)
{
    const int b = blockIdx.x >> 3;
    const int k = blockIdx.x & 7;
    const int d = threadIdx.x;          // 0..255
    const int wave = d >> 6, lane = d & 63;

    float wx = 0.0f, wx2 = 0.0f, sw = 0.0f;
    for (int c = 0; c < C; ++c) {
        const float* p = ws_wx + ((size_t)((b * C + c) * KK + k)) * 512;
        wx  += p[d];
        wx2 += p[256 + d];
        sw  += ws_w[(size_t)(b * C + c) * KK + k];
    }

    const float ck   = centers[k * DD + d];
    const float mean = wx - ck * sw;
    const float E    = wx2 - 2.0f * ck * wx + ck * ck * sw;
    const float var  = E - mean * mean;

    // layernorm over 512 values (each thread holds 2: mean_d, var_d)
    float s1 = mean + var;
    float s2 = mean * mean + var * var;
    #pragma unroll
    for (int off = 32; off >= 1; off >>= 1) {
        s1 += __shfl_xor(s1, off, 64);
        s2 += __shfl_xor(s2, off, 64);
    }
    __shared__ float l1[4], l2[4];
    if (lane == 0) { l1[wave] = s1; l2[wave] = s2; }
    __syncthreads();
    const float S1 = l1[0] + l1[1] + l1[2] + l1[3];
    const float S2 = l2[0] + l2[1] + l2[2] + l2[3];

    const float mu   = S1 * (1.0f / 512.0f);
    const float v    = S2 * (1.0f / 512.0f) - mu * mu;
    const float rinv = rsqrtf(v + LN_EPS);

    const size_t o = (size_t)b * (KK * 512) + (size_t)k * 512;
    out[o + d]       = (mean - mu) * rinv;
    out[o + 256 + d] = (var  - mu) * rinv;
}

// ---------------------------------------------------------------------------
extern "C" void kernel_launch(void* const* d_in, const int* in_sizes, int n_in,
                              void* d_out, int out_size, void* d_ws, size_t ws_size,
                              hipStream_t stream)
{
    const float* x       = (const float*)d_in[0];
    const float* centers = (const float*)d_in[1];
    const float* scale   = (const float*)d_in[2];
    const float* temp    = (const float*)d_in[3];
    float* out = (float*)d_out;

    // pick largest chunk count whose partial buffer fits in ws
    int C = 32;
    while (C > 1 && (size_t)BB * C * KK * (512 + 1) * sizeof(float) > ws_size) C >>= 1;

    float* ws_wx = (float*)d_ws;
    float* ws_w  = ws_wx + (size_t)BB * C * KK * 512;

    dim3 g1(C, BB);
    lde_accum<<<g1, 512, 0, stream>>>(x, centers, scale, temp, ws_wx, ws_w, C);
    lde_final<<<BB * KK, 256, 0, stream>>>(ws_wx, ws_w, centers, out, C);
}